// Round 3
// baseline (1129.503 us; speedup 1.0000x reference)
//
#include <hip/hip_runtime.h>

#define TPB   1024
#define CDIM  192
#define HEADS 6
#define LDX   200   // shorts; row stride 400B: 16B-aligned, ≡4 mod 32 words (2-way, free)
#define LDV   72    // shorts; 144B: 16B-aligned, ≡4 mod 32 words
#define LDP   72
#define SCALE 0.07216878364870323f  // 1/sqrt(192)
#define EPSF  1e-12f

using short8 = __attribute__((ext_vector_type(8))) short;
using f32x4  = __attribute__((ext_vector_type(4))) float;
using us4    = __attribute__((ext_vector_type(4))) unsigned short;

__device__ __forceinline__ unsigned short f2b(float f) {
  union { float f; unsigned u; } a; a.f = f;
  unsigned u = a.u;
  u += 0x7fffu + ((u >> 16) & 1u);
  return (unsigned short)(u >> 16);
}
__device__ __forceinline__ float b2f(unsigned short h) {
  union { unsigned u; float f; } a; a.u = ((unsigned)h) << 16;
  return a.f;
}
#define MFMA(a, b, c) __builtin_amdgcn_mfma_f32_16x16x32_bf16((a), (b), (c), 0, 0, 0)

// ---- pre-kernel: cast weights f32 -> bf16 into workspace ----
#define NWQ  36864
#define NWKV 73728
#define NWP  36864
__global__ void cvt_weights(const float* __restrict__ Wq, const float* __restrict__ Wkv,
                            const float* __restrict__ Wp, unsigned short* __restrict__ o) {
  int i = blockIdx.x * blockDim.x + threadIdx.x;
  if (i < NWQ) o[i] = f2b(Wq[i]);
  else if (i < NWQ + NWKV) o[i] = f2b(Wkv[i - NWQ]);
  else if (i < NWQ + NWKV + NWP) o[i] = f2b(Wp[i - NWQ - NWKV]);
}

// One block per kv-window; handles q-windows {b, b+BKV}.
__global__ __launch_bounds__(TPB, 1) void wa_pair(
    const float* __restrict__ qx, const float* __restrict__ kvx,
    const float* __restrict__ pos,
    const float* __restrict__ bq, const float* __restrict__ bkv,
    const float* __restrict__ bp,
    const unsigned short* __restrict__ Wqb, const unsigned short* __restrict__ Wkvb,
    const unsigned short* __restrict__ Wpb,
    float* __restrict__ out, int BKV)
{
  __shared__ __align__(16) unsigned short sQ[2][64 * LDX];  // qx staged -> Q -> x
  __shared__ __align__(16) unsigned short sK[64 * LDX];     // kvx staged -> K (normalized)
  __shared__ __align__(16) unsigned short sVt[CDIM * LDV];  // V transposed [vcol][kvrow]
  __shared__ __align__(16) unsigned short sP[2][2][64 * LDP]; // P for (win, head-in-pair)

  const int tid = threadIdx.x;
  const int wid = tid >> 6;
  const int lane = tid & 63;
  const int l15 = lane & 15;
  const int l4  = lane >> 4;
  const int b   = blockIdx.x;
  const size_t kvoff = (size_t)b * (64 * CDIM);

  // ============ Phase 1: stage qx0+pos, qx1+pos, kvx (12 loads in flight) ============
  {
    const float4* gq0 = (const float4*)(qx + kvoff);                 // window b
    const float4* gq1 = (const float4*)(qx + (size_t)(b + BKV) * (64 * CDIM));
    const float4* gkv = (const float4*)(kvx + kvoff);
    const float4* p4  = (const float4*)pos;
    float4 rq0[3], rq1[3], rkv[3], rp[3];
    #pragma unroll
    for (int t = 0; t < 3; ++t) {
      int e = tid + t * TPB;
      rq0[t] = gq0[e]; rq1[t] = gq1[e]; rkv[t] = gkv[e]; rp[t] = p4[e];
    }
    #pragma unroll
    for (int t = 0; t < 3; ++t) {
      int e = tid + t * TPB, row = e / 48, c4 = e % 48;
      us4 w0, w1, wk;
      w0.x = f2b(rq0[t].x + rp[t].x); w0.y = f2b(rq0[t].y + rp[t].y);
      w0.z = f2b(rq0[t].z + rp[t].z); w0.w = f2b(rq0[t].w + rp[t].w);
      w1.x = f2b(rq1[t].x + rp[t].x); w1.y = f2b(rq1[t].y + rp[t].y);
      w1.z = f2b(rq1[t].z + rp[t].z); w1.w = f2b(rq1[t].w + rp[t].w);
      wk.x = f2b(rkv[t].x); wk.y = f2b(rkv[t].y); wk.z = f2b(rkv[t].z); wk.w = f2b(rkv[t].w);
      *(us4*)&sQ[0][row * LDX + c4 * 4] = w0;
      *(us4*)&sQ[1][row * LDX + c4 * 4] = w1;
      *(us4*)&sK[row * LDX + c4 * 4] = wk;
    }
  }
  __syncthreads();

  // ============ Phase 2: kv-proj (waves 0-7) || q-proj both windows (waves 8-15) ============
  if (wid < 8) {
    // kv-proj: m-tile = wid&3, n-group = wid>>2 (12 n-tiles each of 24)
    const int m = wid & 3;
    const int ng = (wid >> 2) * 12;
    f32x4 acc[12];
    #pragma unroll
    for (int nn = 0; nn < 12; ++nn) {
      float bv = bkv[(ng + nn) * 16 + l15];
      acc[nn] = f32x4{bv, bv, bv, bv};
    }
    #pragma unroll
    for (int ks = 0; ks < 6; ++ks) {
      short8 a = *(const short8*)&sK[(16 * m + l15) * LDX + ks * 32 + l4 * 8];
      #pragma unroll
      for (int nn = 0; nn < 12; ++nn) {
        short8 bb = *(const short8*)&Wkvb[((ng + nn) * 16 + l15) * CDIM + ks * 32 + l4 * 8];
        acc[nn] = MFMA(a, bb, acc[nn]);
      }
    }
    __syncthreads();  // all reads of staged kvx done
    #pragma unroll
    for (int nn = 0; nn < 12; ++nn) {
      int colg = (ng + nn) * 16 + l15;
      #pragma unroll
      for (int r = 0; r < 4; ++r) {
        int row = 16 * m + l4 * 4 + r;
        unsigned short hv = f2b(acc[nn][r]);
        if (colg < CDIM) sK[row * LDX + colg] = hv;
        else             sVt[(colg - CDIM) * LDV + row] = hv;
      }
    }
  } else {
    // q-proj: m8 = wid-8 (8 m-tiles across 2 windows), all 12 n-tiles
    const int m8 = wid - 8;
    const int win = m8 >> 2;
    const int mw = m8 & 3;
    f32x4 acc[12];
    #pragma unroll
    for (int nn = 0; nn < 12; ++nn) {
      float bv = bq[nn * 16 + l15];
      acc[nn] = f32x4{bv, bv, bv, bv};
    }
    #pragma unroll
    for (int ks = 0; ks < 6; ++ks) {
      short8 a = *(const short8*)&sQ[win][(16 * mw + l15) * LDX + ks * 32 + l4 * 8];
      #pragma unroll
      for (int nn = 0; nn < 12; ++nn) {
        short8 bb = *(const short8*)&Wqb[(nn * 16 + l15) * CDIM + ks * 32 + l4 * 8];
        acc[nn] = MFMA(a, bb, acc[nn]);
      }
    }
    __syncthreads();  // matches kv-proj barrier; own rows already fully read
    #pragma unroll
    for (int nn = 0; nn < 12; ++nn)
      #pragma unroll
      for (int r = 0; r < 4; ++r)
        sQ[win][(16 * mw + l4 * 4 + r) * LDX + nn * 16 + l15] = f2b(acc[nn][r]);
  }
  __syncthreads();

  // ============ Phase 3: fold norms: Q *= SCALE/||q||, K *= 1/||k|| (per row, head) ============
  {
    if (tid < 768) {
      int win = tid >= 384;
      int rem = tid - win * 384;
      int h = rem >> 6, r = rem & 63;
      unsigned short* base = &sQ[win][r * LDX + h * 32];
      short8 v[4];
      float ss = 0.f;
      #pragma unroll
      for (int g = 0; g < 4; ++g) {
        v[g] = *(const short8*)&base[g * 8];
        #pragma unroll
        for (int j = 0; j < 8; ++j) { float f = b2f((unsigned short)v[g][j]); ss += f * f; }
      }
      float sc = SCALE / fmaxf(sqrtf(ss), EPSF);
      #pragma unroll
      for (int g = 0; g < 4; ++g) {
        short8 w;
        #pragma unroll
        for (int j = 0; j < 8; ++j) w[j] = (short)f2b(b2f((unsigned short)v[g][j]) * sc);
        *(short8*)&base[g * 8] = w;
      }
    }
    if (tid < 384) {
      int h = tid >> 6, r = tid & 63;
      unsigned short* base = &sK[r * LDX + h * 32];
      short8 v[4];
      float ss = 0.f;
      #pragma unroll
      for (int g = 0; g < 4; ++g) {
        v[g] = *(const short8*)&base[g * 8];
        #pragma unroll
        for (int j = 0; j < 8; ++j) { float f = b2f((unsigned short)v[g][j]); ss += f * f; }
      }
      float sc = 1.0f / fmaxf(sqrtf(ss), EPSF);
      #pragma unroll
      for (int g = 0; g < 4; ++g) {
        short8 w;
        #pragma unroll
        for (int j = 0; j < 8; ++j) w[j] = (short)f2b(b2f((unsigned short)v[g][j]) * sc);
        *(short8*)&base[g * 8] = w;
      }
    }
  }
  __syncthreads();

  // ============ Phase 4: attention, head-pairs; S stays in registers ============
  // task decode: win = wid>>3, hh = (wid>>2)&1, m = wid&3
  const int a_win = wid >> 3;
  const int a_hh  = (wid >> 2) & 1;
  const int a_m   = wid & 3;
  for (int hp = 0; hp < 3; ++hp) {
    const int h = hp * 2 + a_hh;
    // QK^T: S[16 rows][64 cols] per wave, 4 MFMAs
    short8 aq = *(const short8*)&sQ[a_win][(16 * a_m + l15) * LDX + h * 32 + l4 * 8];
    f32x4 c[4];
    #pragma unroll
    for (int n = 0; n < 4; ++n) {
      short8 bk = *(const short8*)&sK[(16 * n + l15) * LDX + h * 32 + l4 * 8];
      f32x4 z = f32x4{0.f, 0.f, 0.f, 0.f};
      c[n] = MFMA(aq, bk, z);
    }
    // in-register softmax per row (row = l4*4+r, cols 16n+l15 across 16-lane group)
    unsigned short* pbase = &sP[a_win][a_hh][0];
    #pragma unroll
    for (int r = 0; r < 4; ++r) {
      float v0 = c[0][r], v1 = c[1][r], v2 = c[2][r], v3 = c[3][r];
      float mx = fmaxf(fmaxf(v0, v1), fmaxf(v2, v3));
      mx = fmaxf(mx, __shfl_xor(mx, 1));
      mx = fmaxf(mx, __shfl_xor(mx, 2));
      mx = fmaxf(mx, __shfl_xor(mx, 4));
      mx = fmaxf(mx, __shfl_xor(mx, 8));
      v0 = __expf(v0 - mx); v1 = __expf(v1 - mx); v2 = __expf(v2 - mx); v3 = __expf(v3 - mx);
      float sum = v0 + v1 + v2 + v3;
      sum += __shfl_xor(sum, 1);
      sum += __shfl_xor(sum, 2);
      sum += __shfl_xor(sum, 4);
      sum += __shfl_xor(sum, 8);
      float inv = 1.0f / sum;
      int prow = (16 * a_m + l4 * 4 + r) * LDP;
      pbase[prow + 0 * 16 + l15] = f2b(v0 * inv);
      pbase[prow + 1 * 16 + l15] = f2b(v1 * inv);
      pbase[prow + 2 * 16 + l15] = f2b(v2 * inv);
      pbase[prow + 3 * 16 + l15] = f2b(v3 * inv);
    }
    __syncthreads();
    // PV: x[16 rows][32 head-cols] per wave
    {
      short8 pa0 = *(const short8*)&sP[a_win][a_hh][(16 * a_m + l15) * LDP + 0 * 32 + l4 * 8];
      short8 pa1 = *(const short8*)&sP[a_win][a_hh][(16 * a_m + l15) * LDP + 1 * 32 + l4 * 8];
      #pragma unroll
      for (int n = 0; n < 2; ++n) {
        short8 bv0 = *(const short8*)&sVt[(h * 32 + 16 * n + l15) * LDV + 0 * 32 + l4 * 8];
        short8 bv1 = *(const short8*)&sVt[(h * 32 + 16 * n + l15) * LDV + 1 * 32 + l4 * 8];
        f32x4 cx = f32x4{0.f, 0.f, 0.f, 0.f};
        cx = MFMA(pa0, bv0, cx);
        cx = MFMA(pa1, bv1, cx);
        #pragma unroll
        for (int r = 0; r < 4; ++r)
          sQ[a_win][(16 * a_m + l4 * 4 + r) * LDX + h * 32 + 16 * n + l15] = f2b(cx[r]);
      }
    }
    __syncthreads();
  }

  // ============ Phase 5: out-proj both windows ============
  {
    const int m8 = wid >> 1;         // 0..7 over 2 windows
    const int win = m8 >> 2;
    const int mw = m8 & 3;
    const int ng = (wid & 1) * 6;
    f32x4 acc[6];
    #pragma unroll
    for (int nn = 0; nn < 6; ++nn) {
      float bv = bp[(ng + nn) * 16 + l15];
      acc[nn] = f32x4{bv, bv, bv, bv};
    }
    #pragma unroll
    for (int ks = 0; ks < 6; ++ks) {
      short8 a = *(const short8*)&sQ[win][(16 * mw + l15) * LDX + ks * 32 + l4 * 8];
      #pragma unroll
      for (int nn = 0; nn < 6; ++nn) {
        short8 bb = *(const short8*)&Wpb[((ng + nn) * 16 + l15) * CDIM + ks * 32 + l4 * 8];
        acc[nn] = MFMA(a, bb, acc[nn]);
      }
    }
    const size_t qoffw = (size_t)(b + win * BKV) * (64 * CDIM);
    #pragma unroll
    for (int nn = 0; nn < 6; ++nn)
      #pragma unroll
      for (int r = 0; r < 4; ++r)
        out[qoffw + (size_t)(16 * mw + l4 * 4 + r) * CDIM + (ng + nn) * 16 + l15] = acc[nn][r];
  }
}

extern "C" void kernel_launch(void* const* d_in, const int* in_sizes, int n_in,
                              void* d_out, int out_size, void* d_ws, size_t ws_size,
                              hipStream_t stream) {
  const float* qx  = (const float*)d_in[0];
  const float* kvx = (const float*)d_in[1];
  const float* pos = (const float*)d_in[2];
  const float* Wq  = (const float*)d_in[3];
  const float* bq  = (const float*)d_in[4];
  const float* Wkv = (const float*)d_in[5];
  const float* bkv = (const float*)d_in[6];
  const float* Wp  = (const float*)d_in[7];
  const float* bp  = (const float*)d_in[8];
  float* out = (float*)d_out;
  unsigned short* wsb = (unsigned short*)d_ws;

  const int BKV = in_sizes[1] / (64 * CDIM);

  const int ncvt = NWQ + NWKV + NWP;
  cvt_weights<<<(ncvt + 255) / 256, 256, 0, stream>>>(Wq, Wkv, Wp, wsb);

  wa_pair<<<BKV, TPB, 0, stream>>>(qx, kvx, pos, bq, bkv, bp,
                                   wsb, wsb + NWQ, wsb + NWQ + NWKV, out, BKV);
}